// Round 2
// baseline (164.943 us; speedup 1.0000x reference)
//
#include <hip/hip_runtime.h>

#define NN 50000
#define NE 600000
#define DI 128
#define DH 16
#define DC 8

// ---------------- layer-1 GEMM: xl = x @ W1l, xr = x @ W1r ----------------
__global__ __launch_bounds__(256) void k_gemm1(
    const float* __restrict__ x,
    const float* __restrict__ W1l,
    const float* __restrict__ W1r,
    float* __restrict__ xl,
    float* __restrict__ xr)
{
    __shared__ float Wc[DI][32];   // [k][j]: j<16 -> W1l, j>=16 -> W1r
    for (int i = threadIdx.x; i < DI * DH; i += 256) {
        int k = i >> 4, j = i & 15;
        Wc[k][j]      = W1l[i];
        Wc[k][j + 16] = W1r[i];
    }
    __syncthreads();
    int n = blockIdx.x * 256 + threadIdx.x;
    if (n >= NN) return;

    float acc[32];
#pragma unroll
    for (int j = 0; j < 32; ++j) acc[j] = 0.f;

    const float4* xrow = (const float4*)(x + (size_t)n * DI);
#pragma unroll 2
    for (int k4 = 0; k4 < DI / 4; ++k4) {
        float4 xv = xrow[k4];
        float xa[4] = {xv.x, xv.y, xv.z, xv.w};
#pragma unroll
        for (int kk = 0; kk < 4; ++kk) {
            const float4* wr = (const float4*)(Wc[k4 * 4 + kk]);
#pragma unroll
            for (int j4 = 0; j4 < 8; ++j4) {
                float4 w = wr[j4];
                acc[j4 * 4 + 0] += xa[kk] * w.x;
                acc[j4 * 4 + 1] += xa[kk] * w.y;
                acc[j4 * 4 + 2] += xa[kk] * w.z;
                acc[j4 * 4 + 3] += xa[kk] * w.w;
            }
        }
    }
    float4* o1 = (float4*)(xl + (size_t)n * DH);
    float4* o2 = (float4*)(xr + (size_t)n * DH);
#pragma unroll
    for (int q = 0; q < 4; ++q) {
        o1[q] = make_float4(acc[q*4+0], acc[q*4+1], acc[q*4+2], acc[q*4+3]);
        o2[q] = make_float4(acc[16+q*4+0], acc[16+q*4+1], acc[16+q*4+2], acc[16+q*4+3]);
    }
}

// ---------------- degree histogram ----------------
__global__ __launch_bounds__(256) void k_hist(const int* __restrict__ dst, int* __restrict__ deg)
{
    int e = blockIdx.x * 256 + threadIdx.x;
    if (e < NE) atomicAdd(&deg[dst[e]], 1);
}

// ---------------- exclusive scan over deg -> rowstart[NN+1] (single block) ----------------
__global__ __launch_bounds__(1024) void k_scan(const int* __restrict__ deg, int* __restrict__ rowstart)
{
    __shared__ int wsum[16];
    __shared__ int carryS;
    int tid = threadIdx.x;
    int w = tid >> 6, lane = tid & 63;
    if (tid == 0) carryS = 0;
    for (int base = 0; base < NN; base += 1024) {
        int i = base + tid;
        int v = (i < NN) ? deg[i] : 0;
        // wave-inclusive scan
        int s = v;
#pragma unroll
        for (int off = 1; off < 64; off <<= 1) {
            int t = __shfl_up(s, off, 64);
            if (lane >= off) s += t;
        }
        __syncthreads();                       // prior chunk done with wsum/carry (also covers init)
        if (lane == 63) wsum[w] = s;
        __syncthreads();
        if (w == 0) {                          // wave 0 scans the 16 wave totals
            int ws = (lane < 16) ? wsum[lane] : 0;
#pragma unroll
            for (int off = 1; off < 16; off <<= 1) {
                int t = __shfl_up(ws, off, 64);
                if (lane >= off) ws += t;
            }
            if (lane < 16) wsum[lane] = ws;
        }
        __syncthreads();
        int woff = (w > 0) ? wsum[w - 1] : 0;
        int incl = s + woff;
        int c = carryS;
        if (i < NN) rowstart[i] = c + incl - v;  // exclusive
        int total = wsum[15];
        __syncthreads();
        if (tid == 0) carryS = c + total;
    }
    if (threadIdx.x == 0) rowstart[NN] = carryS;
}

// ---------------- CSR fill: csr[rowstart[d] + cursor[d]++] = src ----------------
__global__ __launch_bounds__(256) void k_fill(
    const int* __restrict__ src, const int* __restrict__ dst,
    const int* __restrict__ rowstart, int* __restrict__ cursor, int* __restrict__ csr)
{
    int e = blockIdx.x * 256 + threadIdx.x;
    if (e >= NE) return;
    int d = dst[e];
    int pos = atomicAdd(&cursor[d], 1);
    csr[rowstart[d] + pos] = src[e];
}

// ---------------- gather-mean + finish layer 1: h = relu(mean(xl[nbrs]) + b1 + xr) ----------------
__global__ __launch_bounds__(256) void k_agg1h(
    const int* __restrict__ rowstart, const int* __restrict__ csr,
    const float* __restrict__ xl, const float* __restrict__ xr,
    const float* __restrict__ b1, float* __restrict__ h)
{
    int t = blockIdx.x * 256 + threadIdx.x;
    if (t >= NN * 4) return;
    int n = t >> 2, q = t & 3;
    int beg = rowstart[n], end = rowstart[n + 1];
    float4 a0 = make_float4(0.f, 0.f, 0.f, 0.f);
    float4 a1 = make_float4(0.f, 0.f, 0.f, 0.f);
    int j = beg;
    for (; j + 1 < end; j += 2) {          // 2 independent gather chains
        int s0 = csr[j], s1 = csr[j + 1];
        float4 v0 = *(const float4*)(xl + s0 * DH + q * 4);
        float4 v1 = *(const float4*)(xl + s1 * DH + q * 4);
        a0.x += v0.x; a0.y += v0.y; a0.z += v0.z; a0.w += v0.w;
        a1.x += v1.x; a1.y += v1.y; a1.z += v1.z; a1.w += v1.w;
    }
    if (j < end) {
        int s0 = csr[j];
        float4 v0 = *(const float4*)(xl + s0 * DH + q * 4);
        a0.x += v0.x; a0.y += v0.y; a0.z += v0.z; a0.w += v0.w;
    }
    float inv = 1.0f / fmaxf((float)(end - beg), 1.0f);
    float4 r  = *(const float4*)(xr + t * 4);     // t*4 == n*16 + q*4
    float4 bb = *(const float4*)(b1 + q * 4);
    float4 o;
    o.x = fmaxf((a0.x + a1.x) * inv + bb.x + r.x, 0.f);
    o.y = fmaxf((a0.y + a1.y) * inv + bb.y + r.y, 0.f);
    o.z = fmaxf((a0.z + a1.z) * inv + bb.z + r.z, 0.f);
    o.w = fmaxf((a0.w + a1.w) * inv + bb.w + r.w, 0.f);
    *(float4*)(h + t * 4) = o;
}

// ---------------- layer-2 GEMM: zl = h @ W2l, zr = h @ W2r ----------------
__global__ __launch_bounds__(256) void k_layer2(
    const float* __restrict__ h,
    const float* __restrict__ W2l, const float* __restrict__ W2r,
    float* __restrict__ zl, float* __restrict__ zr)
{
    __shared__ float W2[DH][16];   // [k][j]: j<8 -> W2l, j>=8 -> W2r
    if (threadIdx.x < DH * DC) {
        int k = threadIdx.x >> 3, j = threadIdx.x & 7;
        W2[k][j]     = W2l[threadIdx.x];
        W2[k][j + 8] = W2r[threadIdx.x];
    }
    __syncthreads();
    int n = blockIdx.x * 256 + threadIdx.x;
    if (n >= NN) return;

    const float4* hp = (const float4*)(h + (size_t)n * DH);
    float hv[DH];
#pragma unroll
    for (int qq = 0; qq < 4; ++qq) {
        float4 hq = hp[qq];
        hv[qq*4+0] = hq.x; hv[qq*4+1] = hq.y; hv[qq*4+2] = hq.z; hv[qq*4+3] = hq.w;
    }
    float acc[16];
#pragma unroll
    for (int jj = 0; jj < 16; ++jj) acc[jj] = 0.f;
#pragma unroll
    for (int k = 0; k < DH; ++k) {
        const float4* wr = (const float4*)(W2[k]);
        float hs = hv[k];
#pragma unroll
        for (int j4 = 0; j4 < 4; ++j4) {
            float4 w = wr[j4];
            acc[j4*4+0] += hs * w.x;
            acc[j4*4+1] += hs * w.y;
            acc[j4*4+2] += hs * w.z;
            acc[j4*4+3] += hs * w.w;
        }
    }
    float4* zlo = (float4*)(zl + (size_t)n * DC);
    float4* zro = (float4*)(zr + (size_t)n * DC);
    zlo[0] = make_float4(acc[0], acc[1], acc[2], acc[3]);
    zlo[1] = make_float4(acc[4], acc[5], acc[6], acc[7]);
    zro[0] = make_float4(acc[8], acc[9], acc[10], acc[11]);
    zro[1] = make_float4(acc[12], acc[13], acc[14], acc[15]);
}

// ---------------- gather-mean + finish layer 2: out = mean(zl[nbrs]) + b2 + zr ----------------
__global__ __launch_bounds__(256) void k_agg2out(
    const int* __restrict__ rowstart, const int* __restrict__ csr,
    const float* __restrict__ zl, const float* __restrict__ zr,
    const float* __restrict__ b2, float* __restrict__ out)
{
    int t = blockIdx.x * 256 + threadIdx.x;
    if (t >= NN * 2) return;
    int n = t >> 1, q = t & 1;
    int beg = rowstart[n], end = rowstart[n + 1];
    float4 a0 = make_float4(0.f, 0.f, 0.f, 0.f);
    float4 a1 = make_float4(0.f, 0.f, 0.f, 0.f);
    int j = beg;
    for (; j + 1 < end; j += 2) {
        int s0 = csr[j], s1 = csr[j + 1];
        float4 v0 = *(const float4*)(zl + s0 * DC + q * 4);
        float4 v1 = *(const float4*)(zl + s1 * DC + q * 4);
        a0.x += v0.x; a0.y += v0.y; a0.z += v0.z; a0.w += v0.w;
        a1.x += v1.x; a1.y += v1.y; a1.z += v1.z; a1.w += v1.w;
    }
    if (j < end) {
        int s0 = csr[j];
        float4 v0 = *(const float4*)(zl + s0 * DC + q * 4);
        a0.x += v0.x; a0.y += v0.y; a0.z += v0.z; a0.w += v0.w;
    }
    float inv = 1.0f / fmaxf((float)(end - beg), 1.0f);
    float4 r  = *(const float4*)(zr + t * 4);     // t*4 == n*8 + q*4
    float4 bb = *(const float4*)(b2 + q * 4);
    float4 o;
    o.x = (a0.x + a1.x) * inv + bb.x + r.x;
    o.y = (a0.y + a1.y) * inv + bb.y + r.y;
    o.z = (a0.z + a1.z) * inv + bb.z + r.z;
    o.w = (a0.w + a1.w) * inv + bb.w + r.w;
    *(float4*)(out + t * 4) = o;
}

extern "C" void kernel_launch(void* const* d_in, const int* in_sizes, int n_in,
                              void* d_out, int out_size, void* d_ws, size_t ws_size,
                              hipStream_t stream)
{
    const float* x   = (const float*)d_in[0];
    const int*   ei  = (const int*)d_in[1];
    const float* W1l = (const float*)d_in[2];
    const float* b1  = (const float*)d_in[3];
    const float* W1r = (const float*)d_in[4];
    const float* W2l = (const float*)d_in[5];
    const float* b2  = (const float*)d_in[6];
    const float* W2r = (const float*)d_in[7];
    float* out = (float*)d_out;

    const int* src = ei;
    const int* dst = ei + NE;

    // ---- workspace layout (float arrays first, 16B-aligned) ----
    float* xl = (float*)d_ws;                  // NN*16
    float* xr = xl + NN * DH;                  // NN*16
    float* h  = xr + NN * DH;                  // NN*16
    float* zl = xl;                            // alias: xl dead after k_agg1h
    float* zr = xl + NN * DC;                  // still inside old xl
    int* deg      = (int*)(h + NN * DH);       // NN
    int* cursor   = deg + NN;                  // NN (memset together with deg)
    int* rowstart = cursor + NN;               // NN+1
    int* csr      = rowstart + NN + 1;         // NE
    // total = 9.6MB floats + 3.0MB ints = 12.6MB

    hipMemsetAsync(deg, 0, (size_t)(2 * NN) * sizeof(int), stream);

    k_hist <<<(NE + 255) / 256, 256, 0, stream>>>(dst, deg);
    k_scan <<<1, 1024, 0, stream>>>(deg, rowstart);
    k_gemm1<<<(NN + 255) / 256, 256, 0, stream>>>(x, W1l, W1r, xl, xr);
    k_fill <<<(NE + 255) / 256, 256, 0, stream>>>(src, dst, rowstart, cursor, csr);
    k_agg1h<<<(NN * 4 + 255) / 256, 256, 0, stream>>>(rowstart, csr, xl, xr, b1, h);
    k_layer2<<<(NN + 255) / 256, 256, 0, stream>>>(h, W2l, W2r, zl, zr);
    k_agg2out<<<(NN * 2 + 255) / 256, 256, 0, stream>>>(rowstart, csr, zl, zr, b2, out);
}

// Round 3
// 121.330 us; speedup vs baseline: 1.3595x; 1.3595x over previous
//
#include <hip/hip_runtime.h>

#define NN 50000
#define NE 600000
#define DI 128
#define DH 16
#define DC 8
#define NBLK 196   // ceil(NN/256)

// ---------------- layer-1 GEMM: xl = x @ W1l, xr = x @ W1r ----------------
__global__ __launch_bounds__(256) void k_gemm1(
    const float* __restrict__ x,
    const float* __restrict__ W1l,
    const float* __restrict__ W1r,
    float* __restrict__ xl,
    float* __restrict__ xr)
{
    __shared__ float Wc[DI][32];   // [k][j]: j<16 -> W1l, j>=16 -> W1r
    for (int i = threadIdx.x; i < DI * DH; i += 256) {
        int k = i >> 4, j = i & 15;
        Wc[k][j]      = W1l[i];
        Wc[k][j + 16] = W1r[i];
    }
    __syncthreads();
    int n = blockIdx.x * 256 + threadIdx.x;
    if (n >= NN) return;

    float acc[32];
#pragma unroll
    for (int j = 0; j < 32; ++j) acc[j] = 0.f;

    const float4* xrow = (const float4*)(x + (size_t)n * DI);
#pragma unroll 2
    for (int k4 = 0; k4 < DI / 4; ++k4) {
        float4 xv = xrow[k4];
        float xa[4] = {xv.x, xv.y, xv.z, xv.w};
#pragma unroll
        for (int kk = 0; kk < 4; ++kk) {
            const float4* wr = (const float4*)(Wc[k4 * 4 + kk]);
#pragma unroll
            for (int j4 = 0; j4 < 8; ++j4) {
                float4 w = wr[j4];
                acc[j4 * 4 + 0] += xa[kk] * w.x;
                acc[j4 * 4 + 1] += xa[kk] * w.y;
                acc[j4 * 4 + 2] += xa[kk] * w.z;
                acc[j4 * 4 + 3] += xa[kk] * w.w;
            }
        }
    }
    float4* o1 = (float4*)(xl + (size_t)n * DH);
    float4* o2 = (float4*)(xr + (size_t)n * DH);
#pragma unroll
    for (int q = 0; q < 4; ++q) {
        o1[q] = make_float4(acc[q*4+0], acc[q*4+1], acc[q*4+2], acc[q*4+3]);
        o2[q] = make_float4(acc[16+q*4+0], acc[16+q*4+1], acc[16+q*4+2], acc[16+q*4+3]);
    }
}

// ---------------- degree histogram ----------------
__global__ __launch_bounds__(256) void k_hist(const int* __restrict__ dst, int* __restrict__ deg)
{
    int e = blockIdx.x * 256 + threadIdx.x;
    if (e < NE) atomicAdd(&deg[dst[e]], 1);
}

// ---------------- scan phase A: per-block sums ----------------
__global__ __launch_bounds__(256) void k_blocksum(const int* __restrict__ deg, int* __restrict__ bs)
{
    int i = blockIdx.x * 256 + threadIdx.x;
    int v = (i < NN) ? deg[i] : 0;
#pragma unroll
    for (int off = 32; off; off >>= 1) v += __shfl_xor(v, off, 64);
    __shared__ int ws[4];
    int w = threadIdx.x >> 6, lane = threadIdx.x & 63;
    if (lane == 0) ws[w] = v;
    __syncthreads();
    if (threadIdx.x == 0) bs[blockIdx.x] = ws[0] + ws[1] + ws[2] + ws[3];
}

// ---------------- scan phase B: exclusive scan of NBLK block sums (1 block) ----------------
__global__ __launch_bounds__(256) void k_scanblk(const int* __restrict__ bs, int* __restrict__ boff)
{
    int tid = threadIdx.x, w = tid >> 6, lane = tid & 63;
    int v = (tid < NBLK) ? bs[tid] : 0;
    int s = v;
#pragma unroll
    for (int off = 1; off < 64; off <<= 1) {
        int t = __shfl_up(s, off, 64);
        if (lane >= off) s += t;
    }
    __shared__ int wsum[4];
    if (lane == 63) wsum[w] = s;
    __syncthreads();
    int woff = 0;
    for (int k = 0; k < w; ++k) woff += wsum[k];
    if (tid < NBLK) boff[tid] = woff + s - v;   // exclusive
}

// ---------------- scan phase C: per-block exclusive rescan + offset; writes rowstart & cursor ----------------
__global__ __launch_bounds__(256) void k_scanfinal(
    const int* __restrict__ deg, const int* __restrict__ boff,
    int* __restrict__ rowstart, int* __restrict__ cursor)
{
    int i = blockIdx.x * 256 + threadIdx.x;
    int w = threadIdx.x >> 6, lane = threadIdx.x & 63;
    int v = (i < NN) ? deg[i] : 0;
    int s = v;
#pragma unroll
    for (int off = 1; off < 64; off <<= 1) {
        int t = __shfl_up(s, off, 64);
        if (lane >= off) s += t;
    }
    __shared__ int wsum[4];
    if (lane == 63) wsum[w] = s;
    __syncthreads();
    int woff = 0;
    for (int k = 0; k < w; ++k) woff += wsum[k];
    int ex = boff[blockIdx.x] + woff + s - v;
    if (i < NN) { rowstart[i] = ex; cursor[i] = ex; }
    if (i == 0) rowstart[NN] = NE;
}

// ---------------- CSR fill: csr[cursor[d]++] = src (cursor holds absolute positions) ----------------
__global__ __launch_bounds__(256) void k_fill(
    const int* __restrict__ src, const int* __restrict__ dst,
    int* __restrict__ cursor, int* __restrict__ csr)
{
    int e = blockIdx.x * 256 + threadIdx.x;
    if (e >= NE) return;
    int pos = atomicAdd(&cursor[dst[e]], 1);
    csr[pos] = src[e];
}

// ---------------- gather-mean + finish layer 1: h = relu(mean(xl[nbrs]) + b1 + xr) ----------------
__global__ __launch_bounds__(256) void k_agg1h(
    const int* __restrict__ rowstart, const int* __restrict__ csr,
    const float* __restrict__ xl, const float* __restrict__ xr,
    const float* __restrict__ b1, float* __restrict__ h)
{
    int t = blockIdx.x * 256 + threadIdx.x;
    if (t >= NN * 4) return;
    int n = t >> 2, q = t & 3;
    int beg = rowstart[n], end = rowstart[n + 1];
    float4 a0 = make_float4(0.f, 0.f, 0.f, 0.f);
    float4 a1 = make_float4(0.f, 0.f, 0.f, 0.f);
    int j = beg;
    for (; j + 1 < end; j += 2) {          // 2 independent gather chains
        int s0 = csr[j], s1 = csr[j + 1];
        float4 v0 = *(const float4*)(xl + s0 * DH + q * 4);
        float4 v1 = *(const float4*)(xl + s1 * DH + q * 4);
        a0.x += v0.x; a0.y += v0.y; a0.z += v0.z; a0.w += v0.w;
        a1.x += v1.x; a1.y += v1.y; a1.z += v1.z; a1.w += v1.w;
    }
    if (j < end) {
        int s0 = csr[j];
        float4 v0 = *(const float4*)(xl + s0 * DH + q * 4);
        a0.x += v0.x; a0.y += v0.y; a0.z += v0.z; a0.w += v0.w;
    }
    float inv = 1.0f / fmaxf((float)(end - beg), 1.0f);
    float4 r  = *(const float4*)(xr + t * 4);     // t*4 == n*16 + q*4
    float4 bb = *(const float4*)(b1 + q * 4);
    float4 o;
    o.x = fmaxf((a0.x + a1.x) * inv + bb.x + r.x, 0.f);
    o.y = fmaxf((a0.y + a1.y) * inv + bb.y + r.y, 0.f);
    o.z = fmaxf((a0.z + a1.z) * inv + bb.z + r.z, 0.f);
    o.w = fmaxf((a0.w + a1.w) * inv + bb.w + r.w, 0.f);
    *(float4*)(h + t * 4) = o;
}

// ---------------- layer-2 GEMM: zl = h @ W2l, zr = h @ W2r ----------------
__global__ __launch_bounds__(256) void k_layer2(
    const float* __restrict__ h,
    const float* __restrict__ W2l, const float* __restrict__ W2r,
    float* __restrict__ zl, float* __restrict__ zr)
{
    __shared__ float W2[DH][16];   // [k][j]: j<8 -> W2l, j>=8 -> W2r
    if (threadIdx.x < DH * DC) {
        int k = threadIdx.x >> 3, j = threadIdx.x & 7;
        W2[k][j]     = W2l[threadIdx.x];
        W2[k][j + 8] = W2r[threadIdx.x];
    }
    __syncthreads();
    int n = blockIdx.x * 256 + threadIdx.x;
    if (n >= NN) return;

    const float4* hp = (const float4*)(h + (size_t)n * DH);
    float hv[DH];
#pragma unroll
    for (int qq = 0; qq < 4; ++qq) {
        float4 hq = hp[qq];
        hv[qq*4+0] = hq.x; hv[qq*4+1] = hq.y; hv[qq*4+2] = hq.z; hv[qq*4+3] = hq.w;
    }
    float acc[16];
#pragma unroll
    for (int jj = 0; jj < 16; ++jj) acc[jj] = 0.f;
#pragma unroll
    for (int k = 0; k < DH; ++k) {
        const float4* wr = (const float4*)(W2[k]);
        float hs = hv[k];
#pragma unroll
        for (int j4 = 0; j4 < 4; ++j4) {
            float4 w = wr[j4];
            acc[j4*4+0] += hs * w.x;
            acc[j4*4+1] += hs * w.y;
            acc[j4*4+2] += hs * w.z;
            acc[j4*4+3] += hs * w.w;
        }
    }
    float4* zlo = (float4*)(zl + (size_t)n * DC);
    float4* zro = (float4*)(zr + (size_t)n * DC);
    zlo[0] = make_float4(acc[0], acc[1], acc[2], acc[3]);
    zlo[1] = make_float4(acc[4], acc[5], acc[6], acc[7]);
    zro[0] = make_float4(acc[8], acc[9], acc[10], acc[11]);
    zro[1] = make_float4(acc[12], acc[13], acc[14], acc[15]);
}

// ---------------- gather-mean + finish layer 2: out = mean(zl[nbrs]) + b2 + zr ----------------
__global__ __launch_bounds__(256) void k_agg2out(
    const int* __restrict__ rowstart, const int* __restrict__ csr,
    const float* __restrict__ zl, const float* __restrict__ zr,
    const float* __restrict__ b2, float* __restrict__ out)
{
    int t = blockIdx.x * 256 + threadIdx.x;
    if (t >= NN * 2) return;
    int n = t >> 1, q = t & 1;
    int beg = rowstart[n], end = rowstart[n + 1];
    float4 a0 = make_float4(0.f, 0.f, 0.f, 0.f);
    float4 a1 = make_float4(0.f, 0.f, 0.f, 0.f);
    int j = beg;
    for (; j + 1 < end; j += 2) {
        int s0 = csr[j], s1 = csr[j + 1];
        float4 v0 = *(const float4*)(zl + s0 * DC + q * 4);
        float4 v1 = *(const float4*)(zl + s1 * DC + q * 4);
        a0.x += v0.x; a0.y += v0.y; a0.z += v0.z; a0.w += v0.w;
        a1.x += v1.x; a1.y += v1.y; a1.z += v1.z; a1.w += v1.w;
    }
    if (j < end) {
        int s0 = csr[j];
        float4 v0 = *(const float4*)(zl + s0 * DC + q * 4);
        a0.x += v0.x; a0.y += v0.y; a0.z += v0.z; a0.w += v0.w;
    }
    float inv = 1.0f / fmaxf((float)(end - beg), 1.0f);
    float4 r  = *(const float4*)(zr + t * 4);     // t*4 == n*8 + q*4
    float4 bb = *(const float4*)(b2 + q * 4);
    float4 o;
    o.x = (a0.x + a1.x) * inv + bb.x + r.x;
    o.y = (a0.y + a1.y) * inv + bb.y + r.y;
    o.z = (a0.z + a1.z) * inv + bb.z + r.z;
    o.w = (a0.w + a1.w) * inv + bb.w + r.w;
    *(float4*)(out + t * 4) = o;
}

extern "C" void kernel_launch(void* const* d_in, const int* in_sizes, int n_in,
                              void* d_out, int out_size, void* d_ws, size_t ws_size,
                              hipStream_t stream)
{
    const float* x   = (const float*)d_in[0];
    const int*   ei  = (const int*)d_in[1];
    const float* W1l = (const float*)d_in[2];
    const float* b1  = (const float*)d_in[3];
    const float* W1r = (const float*)d_in[4];
    const float* W2l = (const float*)d_in[5];
    const float* b2  = (const float*)d_in[6];
    const float* W2r = (const float*)d_in[7];
    float* out = (float*)d_out;

    const int* src = ei;
    const int* dst = ei + NE;

    // ---- workspace layout (float arrays first, 16B-aligned) ----
    float* xl = (float*)d_ws;                  // NN*16
    float* xr = xl + NN * DH;                  // NN*16
    float* h  = xr + NN * DH;                  // NN*16
    float* zl = xl;                            // alias: xl dead after k_agg1h
    float* zr = xl + NN * DC;                  // still inside old xl
    int* deg      = (int*)(h + NN * DH);       // NN
    int* cursor   = deg + NN;                  // NN
    int* rowstart = cursor + NN;               // NN+1
    int* csr      = rowstart + NN + 1;         // NE
    int* bs       = csr + NE;                  // NBLK
    int* boff     = bs + NBLK;                 // NBLK
    // total ~12.6 MB

    hipMemsetAsync(deg, 0, (size_t)NN * sizeof(int), stream);

    k_hist     <<<(NE + 255) / 256, 256, 0, stream>>>(dst, deg);
    k_blocksum <<<NBLK, 256, 0, stream>>>(deg, bs);
    k_scanblk  <<<1, 256, 0, stream>>>(bs, boff);
    k_scanfinal<<<NBLK, 256, 0, stream>>>(deg, boff, rowstart, cursor);
    k_gemm1    <<<(NN + 255) / 256, 256, 0, stream>>>(x, W1l, W1r, xl, xr);
    k_fill     <<<(NE + 255) / 256, 256, 0, stream>>>(src, dst, cursor, csr);
    k_agg1h    <<<(NN * 4 + 255) / 256, 256, 0, stream>>>(rowstart, csr, xl, xr, b1, h);
    k_layer2   <<<(NN + 255) / 256, 256, 0, stream>>>(h, W2l, W2r, zl, zr);
    k_agg2out  <<<(NN * 2 + 255) / 256, 256, 0, stream>>>(rowstart, csr, zl, zr, b2, out);
}

// Round 4
// 116.931 us; speedup vs baseline: 1.4106x; 1.0376x over previous
//
#include <hip/hip_runtime.h>

#define NN 50000
#define NE 600000
#define DI 128
#define DH 16
#define DC 8
#define NBLK 196   // ceil(NN/256)

// ---------------- layer-1 GEMM: xl = x @ W1l, xr = x @ W1r (+ zero deg) ----------------
__global__ __launch_bounds__(256) void k_gemm1(
    const float* __restrict__ x,
    const float* __restrict__ W1l,
    const float* __restrict__ W1r,
    float* __restrict__ xl,
    float* __restrict__ xr,
    int* __restrict__ deg)
{
    int n = blockIdx.x * 256 + threadIdx.x;
    if (n < NN) deg[n] = 0;                 // fused zero-init (replaces 43us runtime fill)

    __shared__ float Wc[DI][32];   // [k][j]: j<16 -> W1l, j>=16 -> W1r
    for (int i = threadIdx.x; i < DI * DH; i += 256) {
        int k = i >> 4, j = i & 15;
        Wc[k][j]      = W1l[i];
        Wc[k][j + 16] = W1r[i];
    }
    __syncthreads();
    if (n >= NN) return;

    float acc[32];
#pragma unroll
    for (int j = 0; j < 32; ++j) acc[j] = 0.f;

    const float4* xrow = (const float4*)(x + (size_t)n * DI);
#pragma unroll 2
    for (int k4 = 0; k4 < DI / 4; ++k4) {
        float4 xv = xrow[k4];
        float xa[4] = {xv.x, xv.y, xv.z, xv.w};
#pragma unroll
        for (int kk = 0; kk < 4; ++kk) {
            const float4* wr = (const float4*)(Wc[k4 * 4 + kk]);
#pragma unroll
            for (int j4 = 0; j4 < 8; ++j4) {
                float4 w = wr[j4];
                acc[j4 * 4 + 0] += xa[kk] * w.x;
                acc[j4 * 4 + 1] += xa[kk] * w.y;
                acc[j4 * 4 + 2] += xa[kk] * w.z;
                acc[j4 * 4 + 3] += xa[kk] * w.w;
            }
        }
    }
    float4* o1 = (float4*)(xl + (size_t)n * DH);
    float4* o2 = (float4*)(xr + (size_t)n * DH);
#pragma unroll
    for (int q = 0; q < 4; ++q) {
        o1[q] = make_float4(acc[q*4+0], acc[q*4+1], acc[q*4+2], acc[q*4+3]);
        o2[q] = make_float4(acc[16+q*4+0], acc[16+q*4+1], acc[16+q*4+2], acc[16+q*4+3]);
    }
}

// ---------------- degree histogram ----------------
__global__ __launch_bounds__(256) void k_hist(const int* __restrict__ dst, int* __restrict__ deg)
{
    int e = blockIdx.x * 256 + threadIdx.x;
    if (e < NE) atomicAdd(&deg[dst[e]], 1);
}

// ---------------- scan phase A: per-block sums ----------------
__global__ __launch_bounds__(256) void k_blocksum(const int* __restrict__ deg, int* __restrict__ bs)
{
    int i = blockIdx.x * 256 + threadIdx.x;
    int v = (i < NN) ? deg[i] : 0;
#pragma unroll
    for (int off = 32; off; off >>= 1) v += __shfl_xor(v, off, 64);
    __shared__ int ws[4];
    int w = threadIdx.x >> 6, lane = threadIdx.x & 63;
    if (lane == 0) ws[w] = v;
    __syncthreads();
    if (threadIdx.x == 0) bs[blockIdx.x] = ws[0] + ws[1] + ws[2] + ws[3];
}

// ---------------- scan phase B: exclusive scan of NBLK block sums (1 block) ----------------
__global__ __launch_bounds__(256) void k_scanblk(const int* __restrict__ bs, int* __restrict__ boff)
{
    int tid = threadIdx.x, w = tid >> 6, lane = tid & 63;
    int v = (tid < NBLK) ? bs[tid] : 0;
    int s = v;
#pragma unroll
    for (int off = 1; off < 64; off <<= 1) {
        int t = __shfl_up(s, off, 64);
        if (lane >= off) s += t;
    }
    __shared__ int wsum[4];
    if (lane == 63) wsum[w] = s;
    __syncthreads();
    int woff = 0;
    for (int k = 0; k < w; ++k) woff += wsum[k];
    if (tid < NBLK) boff[tid] = woff + s - v;   // exclusive
}

// ---------------- scan phase C: per-block rescan + offset; writes rowstart & cursor ----------------
__global__ __launch_bounds__(256) void k_scanfinal(
    const int* __restrict__ deg, const int* __restrict__ boff,
    int* __restrict__ rowstart, int* __restrict__ cursor)
{
    int i = blockIdx.x * 256 + threadIdx.x;
    int w = threadIdx.x >> 6, lane = threadIdx.x & 63;
    int v = (i < NN) ? deg[i] : 0;
    int s = v;
#pragma unroll
    for (int off = 1; off < 64; off <<= 1) {
        int t = __shfl_up(s, off, 64);
        if (lane >= off) s += t;
    }
    __shared__ int wsum[4];
    if (lane == 63) wsum[w] = s;
    __syncthreads();
    int woff = 0;
    for (int k = 0; k < w; ++k) woff += wsum[k];
    int ex = boff[blockIdx.x] + woff + s - v;
    if (i < NN) { rowstart[i] = ex; cursor[i] = ex; }
    if (i == 0) rowstart[NN] = NE;
}

// ---------------- CSR fill: csr[cursor[d]++] = src (cursor holds absolute positions) ----------------
__global__ __launch_bounds__(256) void k_fill(
    const int* __restrict__ src, const int* __restrict__ dst,
    int* __restrict__ cursor, int* __restrict__ csr)
{
    int e = blockIdx.x * 256 + threadIdx.x;
    if (e >= NE) return;
    int pos = atomicAdd(&cursor[dst[e]], 1);
    csr[pos] = src[e];
}

// ---------------- gather-mean + finish layer 1: h = relu(mean(xl[nbrs]) + b1 + xr) ----------------
__global__ __launch_bounds__(256) void k_agg1h(
    const int* __restrict__ rowstart, const int* __restrict__ csr,
    const float* __restrict__ xl, const float* __restrict__ xr,
    const float* __restrict__ b1, float* __restrict__ h)
{
    int t = blockIdx.x * 256 + threadIdx.x;
    if (t >= NN * 4) return;
    int n = t >> 2, q = t & 3;
    int beg = rowstart[n], end = rowstart[n + 1];
    float4 a0 = make_float4(0.f, 0.f, 0.f, 0.f);
    float4 a1 = make_float4(0.f, 0.f, 0.f, 0.f);
    int j = beg;
    for (; j + 1 < end; j += 2) {          // 2 independent gather chains
        int s0 = csr[j], s1 = csr[j + 1];
        float4 v0 = *(const float4*)(xl + s0 * DH + q * 4);
        float4 v1 = *(const float4*)(xl + s1 * DH + q * 4);
        a0.x += v0.x; a0.y += v0.y; a0.z += v0.z; a0.w += v0.w;
        a1.x += v1.x; a1.y += v1.y; a1.z += v1.z; a1.w += v1.w;
    }
    if (j < end) {
        int s0 = csr[j];
        float4 v0 = *(const float4*)(xl + s0 * DH + q * 4);
        a0.x += v0.x; a0.y += v0.y; a0.z += v0.z; a0.w += v0.w;
    }
    float inv = 1.0f / fmaxf((float)(end - beg), 1.0f);
    float4 r  = *(const float4*)(xr + t * 4);     // t*4 == n*16 + q*4
    float4 bb = *(const float4*)(b1 + q * 4);
    float4 o;
    o.x = fmaxf((a0.x + a1.x) * inv + bb.x + r.x, 0.f);
    o.y = fmaxf((a0.y + a1.y) * inv + bb.y + r.y, 0.f);
    o.z = fmaxf((a0.z + a1.z) * inv + bb.z + r.z, 0.f);
    o.w = fmaxf((a0.w + a1.w) * inv + bb.w + r.w, 0.f);
    *(float4*)(h + t * 4) = o;
}

// ---------------- layer-2 GEMM: zl = h @ W2l, zr = h @ W2r ----------------
__global__ __launch_bounds__(256) void k_layer2(
    const float* __restrict__ h,
    const float* __restrict__ W2l, const float* __restrict__ W2r,
    float* __restrict__ zl, float* __restrict__ zr)
{
    __shared__ float W2[DH][16];   // [k][j]: j<8 -> W2l, j>=8 -> W2r
    if (threadIdx.x < DH * DC) {
        int k = threadIdx.x >> 3, j = threadIdx.x & 7;
        W2[k][j]     = W2l[threadIdx.x];
        W2[k][j + 8] = W2r[threadIdx.x];
    }
    __syncthreads();
    int n = blockIdx.x * 256 + threadIdx.x;
    if (n >= NN) return;

    const float4* hp = (const float4*)(h + (size_t)n * DH);
    float hv[DH];
#pragma unroll
    for (int qq = 0; qq < 4; ++qq) {
        float4 hq = hp[qq];
        hv[qq*4+0] = hq.x; hv[qq*4+1] = hq.y; hv[qq*4+2] = hq.z; hv[qq*4+3] = hq.w;
    }
    float acc[16];
#pragma unroll
    for (int jj = 0; jj < 16; ++jj) acc[jj] = 0.f;
#pragma unroll
    for (int k = 0; k < DH; ++k) {
        const float4* wr = (const float4*)(W2[k]);
        float hs = hv[k];
#pragma unroll
        for (int j4 = 0; j4 < 4; ++j4) {
            float4 w = wr[j4];
            acc[j4*4+0] += hs * w.x;
            acc[j4*4+1] += hs * w.y;
            acc[j4*4+2] += hs * w.z;
            acc[j4*4+3] += hs * w.w;
        }
    }
    float4* zlo = (float4*)(zl + (size_t)n * DC);
    float4* zro = (float4*)(zr + (size_t)n * DC);
    zlo[0] = make_float4(acc[0], acc[1], acc[2], acc[3]);
    zlo[1] = make_float4(acc[4], acc[5], acc[6], acc[7]);
    zro[0] = make_float4(acc[8], acc[9], acc[10], acc[11]);
    zro[1] = make_float4(acc[12], acc[13], acc[14], acc[15]);
}

// ---------------- gather-mean + finish layer 2: out = mean(zl[nbrs]) + b2 + zr ----------------
__global__ __launch_bounds__(256) void k_agg2out(
    const int* __restrict__ rowstart, const int* __restrict__ csr,
    const float* __restrict__ zl, const float* __restrict__ zr,
    const float* __restrict__ b2, float* __restrict__ out)
{
    int t = blockIdx.x * 256 + threadIdx.x;
    if (t >= NN * 2) return;
    int n = t >> 1, q = t & 1;
    int beg = rowstart[n], end = rowstart[n + 1];
    float4 a0 = make_float4(0.f, 0.f, 0.f, 0.f);
    float4 a1 = make_float4(0.f, 0.f, 0.f, 0.f);
    int j = beg;
    for (; j + 1 < end; j += 2) {
        int s0 = csr[j], s1 = csr[j + 1];
        float4 v0 = *(const float4*)(zl + s0 * DC + q * 4);
        float4 v1 = *(const float4*)(zl + s1 * DC + q * 4);
        a0.x += v0.x; a0.y += v0.y; a0.z += v0.z; a0.w += v0.w;
        a1.x += v1.x; a1.y += v1.y; a1.z += v1.z; a1.w += v1.w;
    }
    if (j < end) {
        int s0 = csr[j];
        float4 v0 = *(const float4*)(zl + s0 * DC + q * 4);
        a0.x += v0.x; a0.y += v0.y; a0.z += v0.z; a0.w += v0.w;
    }
    float inv = 1.0f / fmaxf((float)(end - beg), 1.0f);
    float4 r  = *(const float4*)(zr + t * 4);     // t*4 == n*8 + q*4
    float4 bb = *(const float4*)(b2 + q * 4);
    float4 o;
    o.x = (a0.x + a1.x) * inv + bb.x + r.x;
    o.y = (a0.y + a1.y) * inv + bb.y + r.y;
    o.z = (a0.z + a1.z) * inv + bb.z + r.z;
    o.w = (a0.w + a1.w) * inv + bb.w + r.w;
    *(float4*)(out + t * 4) = o;
}

extern "C" void kernel_launch(void* const* d_in, const int* in_sizes, int n_in,
                              void* d_out, int out_size, void* d_ws, size_t ws_size,
                              hipStream_t stream)
{
    const float* x   = (const float*)d_in[0];
    const int*   ei  = (const int*)d_in[1];
    const float* W1l = (const float*)d_in[2];
    const float* b1  = (const float*)d_in[3];
    const float* W1r = (const float*)d_in[4];
    const float* W2l = (const float*)d_in[5];
    const float* b2  = (const float*)d_in[6];
    const float* W2r = (const float*)d_in[7];
    float* out = (float*)d_out;

    const int* src = ei;
    const int* dst = ei + NE;

    // ---- workspace layout (float arrays first, 16B-aligned) ----
    float* xl = (float*)d_ws;                  // NN*16
    float* xr = xl + NN * DH;                  // NN*16
    float* h  = xr + NN * DH;                  // NN*16
    float* zl = xl;                            // alias: xl dead after k_agg1h
    float* zr = xl + NN * DC;                  // still inside old xl
    int* deg      = (int*)(h + NN * DH);       // NN
    int* cursor   = deg + NN;                  // NN
    int* rowstart = cursor + NN;               // NN+1
    int* csr      = rowstart + NN + 1;         // NE
    int* bs       = csr + NE;                  // NBLK
    int* boff     = bs + NBLK;                 // NBLK
    // total ~12.6 MB

    k_gemm1    <<<NBLK, 256, 0, stream>>>(x, W1l, W1r, xl, xr, deg);
    k_hist     <<<(NE + 255) / 256, 256, 0, stream>>>(dst, deg);
    k_blocksum <<<NBLK, 256, 0, stream>>>(deg, bs);
    k_scanblk  <<<1, 256, 0, stream>>>(bs, boff);
    k_scanfinal<<<NBLK, 256, 0, stream>>>(deg, boff, rowstart, cursor);
    k_fill     <<<(NE + 255) / 256, 256, 0, stream>>>(src, dst, cursor, csr);
    k_agg1h    <<<(NN * 4 + 255) / 256, 256, 0, stream>>>(rowstart, csr, xl, xr, b1, h);
    k_layer2   <<<(NN + 255) / 256, 256, 0, stream>>>(h, W2l, W2r, zl, zr);
    k_agg2out  <<<(NN * 2 + 255) / 256, 256, 0, stream>>>(rowstart, csr, zl, zr, b2, out);
}